// Round 1
// baseline (217.863 us; speedup 1.0000x reference)
//
#include <hip/hip_runtime.h>
#include <math.h>

#define N_NODES 2048
#define N_EDGES 4096
#define PI_F 3.14159265358979323846f
#define TWO_PI_F 6.28318530717958647692f

__device__ __forceinline__ float shflx(float v, int m) {
    return __shfl_xor(v, m, 64);
}

// ---------------- statevector gate helpers ----------------
// Amplitude index = lane*NA + j. j bits are "in-register" bits, lane bits sit above.
// RY pair semantics (reference): new0 = c*s0 - s*s1 ; new1 = s*s0 + c*s1.

template<int NA, int B>
__device__ __forceinline__ void ry_j(float* a, float c, float s) {
#pragma unroll
    for (int j = 0; j < NA; ++j) {
        if ((j & (1 << B)) == 0) {
            int k = j | (1 << B);
            float x0 = a[j], x1 = a[k];
            a[j] = c * x0 - s * x1;
            a[k] = s * x0 + c * x1;
        }
    }
}

template<int NA, int LB>
__device__ __forceinline__ void ry_l(float* a, float c, float s, int lane) {
    float ss = ((lane >> LB) & 1) ? s : -s;   // bit==0: c*a - s*p ; bit==1: c*a + s*p
#pragma unroll
    for (int j = 0; j < NA; ++j) {
        float p = shflx(a[j], 1 << LB);
        a[j] = c * a[j] + ss * p;
    }
}

// CNOT: for amplitudes with ctrl bit == 1, flip tgt bit.
template<int NA, int BC, int BT>
__device__ __forceinline__ void cx_jj(float* a) {
#pragma unroll
    for (int j = 0; j < NA; ++j) {
        if ((j & (1 << BC)) && !(j & (1 << BT))) {
            int k = j | (1 << BT);
            float t = a[j]; a[j] = a[k]; a[k] = t;
        }
    }
}

template<int NA, int BC, int LT>
__device__ __forceinline__ void cx_jl(float* a) {
#pragma unroll
    for (int j = 0; j < NA; ++j)
        if (j & (1 << BC)) a[j] = shflx(a[j], 1 << LT);
}

template<int NA, int LC, int BT>
__device__ __forceinline__ void cx_lj(float* a, int lane) {
    bool sel = ((lane >> LC) & 1) != 0;
#pragma unroll
    for (int j = 0; j < NA; ++j) {
        if ((j & (1 << BT)) == 0) {
            int k = j | (1 << BT);
            float t0 = a[j], t1 = a[k];
            a[j] = sel ? t1 : t0;
            a[k] = sel ? t0 : t1;
        }
    }
}

template<int NA, int LC, int LT>
__device__ __forceinline__ void cx_ll(float* a, int lane) {
    bool sel = ((lane >> LC) & 1) != 0;
#pragma unroll
    for (int j = 0; j < NA; ++j) {
        float p = shflx(a[j], 1 << LT);
        a[j] = sel ? p : a[j];
    }
}

#define RY_L(NA, LB, ANG) do { float c_, sn_; sincosf(0.5f*(ANG), &sn_, &c_); ry_l<NA,LB>(a, c_, sn_, lane); } while(0)
#define RY_J(NA, BB, ANG) do { float c_, sn_; sincosf(0.5f*(ANG), &sn_, &c_); ry_j<NA,BB>(a, c_, sn_); } while(0)

// ---------------- setup: H0 + index extraction ----------------
// Ri/Ro are one-hot (N,E): Ri[recv[e],e]=1, Ro[send[e],e]=1. One float4 per thread.
__global__ __launch_bounds__(256) void k_setup(
        const float* __restrict__ X, const float* __restrict__ Ri,
        const float* __restrict__ Ro, const float* __restrict__ W,
        const float* __restrict__ b,
        int* __restrict__ send, int* __restrict__ recv, float* __restrict__ H) {
    int tid = blockIdx.x * blockDim.x + threadIdx.x;
    if (tid < N_NODES) {
        float x0 = X[tid*3+0], x1 = X[tid*3+1], x2 = X[tid*3+2];
        float z = x0*W[0] + x1*W[1] + x2*W[2] + b[0];
        float sg = 1.0f / (1.0f + expf(-z));
        H[tid*4+0] = sg * TWO_PI_F;
        H[tid*4+1] = x0; H[tid*4+2] = x1; H[tid*4+3] = x2;
    }
    const float4 vi = ((const float4*)Ri)[tid];
    const float4 vo = ((const float4*)Ro)[tid];
    int base = tid * 4;
    int n = base >> 12;             // row (E = 4096)
    int e = base & (N_EDGES - 1);   // col
    if (vi.x != 0.f) recv[e+0] = n;
    if (vi.y != 0.f) recv[e+1] = n;
    if (vi.z != 0.f) recv[e+2] = n;
    if (vi.w != 0.f) recv[e+3] = n;
    if (vo.x != 0.f) send[e+0] = n;
    if (vo.y != 0.f) send[e+1] = n;
    if (vo.z != 0.f) send[e+2] = n;
    if (vo.w != 0.f) send[e+3] = n;
}

// ---------------- edge circuit: n=8, one wave per edge, 4 amps/lane ----------------
// wire w -> bit 7-w. bits[7:2]=lane bits 5..0, bits[1:0]=j bits 1..0.
// w0:L5 w1:L4 w2:L3 w3:L2 w4:L1 w5:L0 w6:J1 w7:J0. Measure wire5 -> lane bit 0.
__global__ __launch_bounds__(256) void k_edge(
        const float* __restrict__ H, const int* __restrict__ send,
        const int* __restrict__ recv, const float* __restrict__ th,
        float* __restrict__ out) {
    int wave = (blockIdx.x * blockDim.x + threadIdx.x) >> 6;
    int lane = threadIdx.x & 63;
    int si = send[wave], ri = recv[wave];
    float B[8];
#pragma unroll
    for (int k = 0; k < 4; ++k) { B[k] = H[si*4+k]; B[4+k] = H[ri*4+k]; }

    float a[4];
    a[0] = (lane == 0) ? 1.0f : 0.0f;
    a[1] = 0.f; a[2] = 0.f; a[3] = 0.f;

    // input encoding
    RY_L(4,5,B[0]); RY_L(4,4,B[1]); RY_L(4,3,B[2]); RY_L(4,2,B[3]);
    RY_L(4,1,B[4]); RY_L(4,0,B[5]); RY_J(4,1,B[6]); RY_J(4,0,B[7]);
    // EDGE_OPS
    RY_L(4,5,th[0]);  RY_L(4,4,th[1]);  cx_ll<4,5,4>(a, lane);
    RY_L(4,3,th[2]);  RY_L(4,2,th[3]);  cx_ll<4,2,3>(a, lane);
    RY_L(4,1,th[4]);  RY_L(4,0,th[5]);  cx_ll<4,1,0>(a, lane);
    RY_J(4,1,th[6]);  RY_J(4,0,th[7]);  cx_jj<4,0,1>(a);
    RY_L(4,4,th[8]);  RY_L(4,3,th[9]);  cx_ll<4,4,3>(a, lane);
    RY_L(4,0,th[10]); RY_J(4,1,th[11]); cx_jl<4,1,0>(a);
    RY_L(4,3,th[12]); RY_L(4,0,th[13]); cx_ll<4,3,0>(a, lane);
    RY_L(4,0,th[14]);

    float p = a[0]*a[0] + a[1]*a[1] + a[2]*a[2] + a[3]*a[3];
    p = (lane & 1) ? -p : p;
#pragma unroll
    for (int m = 32; m; m >>= 1) p += shflx(p, m);
    if (lane == 0) out[wave] = (1.0f - p) * 0.5f;
}

// ---------------- message scatter: mi/mo accumulators ----------------
__global__ __launch_bounds__(256) void k_scatter(
        const float* __restrict__ ebuf, const int* __restrict__ send,
        const int* __restrict__ recv, const float* __restrict__ H,
        float* __restrict__ macc) {
    int e = blockIdx.x * blockDim.x + threadIdx.x;
    if (e >= N_EDGES) return;
    float ev = ebuf[e];
    int s = send[e], r = recv[e];
#pragma unroll
    for (int k = 0; k < 4; ++k) {
        atomicAdd(&macc[r*8 + k],     ev * H[s*4 + k]);   // mi[recv] += e * bo(=H[send])
        atomicAdd(&macc[s*8 + 4 + k], ev * H[r*4 + k]);   // mo[send] += e * bi(=H[recv])
    }
}

// ---------------- node circuit: n=12, one wave per node, 64 amps/lane ----------------
// wire w -> bit 11-w. bits[11:6]=lane bits 5..0, bits[5:0]=j bits 5..0.
// w0:L5 w1:L4 w2:L3 w3:L2 w4:L1 w5:L0 w6:J5 w7:J4 w8:J3 w9:J2 w10:J1 w11:J0.
// Measure wire9 -> j bit 2. Writes H[n*4] = pi*(1-<Z>), in place.
__global__ __launch_bounds__(256) void k_node(
        const float* __restrict__ macc, float* __restrict__ H,
        const float* __restrict__ th) {
    int wave = (blockIdx.x * blockDim.x + threadIdx.x) >> 6;
    int lane = threadIdx.x & 63;
    int n = wave;
    float M[12];
#pragma unroll
    for (int k = 0; k < 8; ++k) M[k] = macc[n*8+k];
#pragma unroll
    for (int k = 0; k < 4; ++k) M[8+k] = H[n*4+k];

    float a[64];
#pragma unroll
    for (int j = 0; j < 64; ++j) a[j] = 0.f;
    if (lane == 0) a[0] = 1.0f;

    // input encoding, wires 0..11
    RY_L(64,5,M[0]); RY_L(64,4,M[1]); RY_L(64,3,M[2]); RY_L(64,2,M[3]);
    RY_L(64,1,M[4]); RY_L(64,0,M[5]);
    RY_J(64,5,M[6]); RY_J(64,4,M[7]); RY_J(64,3,M[8]); RY_J(64,2,M[9]);
    RY_J(64,1,M[10]); RY_J(64,0,M[11]);
    // NODE_OPS
    RY_L(64,5,th[0]);  RY_L(64,4,th[1]);  cx_ll<64,5,4>(a, lane);
    RY_L(64,3,th[2]);  RY_L(64,2,th[3]);  cx_ll<64,2,3>(a, lane);
    RY_L(64,1,th[4]);  RY_L(64,0,th[5]);  cx_ll<64,1,0>(a, lane);
    RY_J(64,5,th[6]);  RY_J(64,4,th[7]);  cx_jj<64,4,5>(a);
    RY_J(64,3,th[8]);  RY_J(64,2,th[9]);  cx_jj<64,3,2>(a);
    RY_J(64,1,th[10]); RY_J(64,0,th[11]); cx_jj<64,0,1>(a);
    RY_L(64,4,th[12]); RY_L(64,3,th[13]); cx_ll<64,4,3>(a, lane);
    RY_L(64,0,th[14]); RY_J(64,5,th[15]); cx_jl<64,5,0>(a);
    RY_J(64,2,th[16]); RY_J(64,1,th[17]); cx_jj<64,1,2>(a);
    RY_L(64,3,th[18]); RY_L(64,0,th[19]); cx_ll<64,3,0>(a, lane);
    RY_L(64,0,th[20]); RY_J(64,2,th[21]); cx_lj<64,0,2>(a, lane);
    RY_L(64,1,th[22]);

    float p = 0.f;
#pragma unroll
    for (int j = 0; j < 64; ++j) {
        float q = a[j]*a[j];
        p += (j & 4) ? -q : q;
    }
#pragma unroll
    for (int m = 32; m; m >>= 1) p += shflx(p, m);
    if (lane == 0) H[n*4+0] = PI_F * (1.0f - p);   // X part of H unchanged
}

extern "C" void kernel_launch(void* const* d_in, const int* in_sizes, int n_in,
                              void* d_out, int out_size, void* d_ws, size_t ws_size,
                              hipStream_t stream) {
    const float* X  = (const float*)d_in[0];
    const float* Ri = (const float*)d_in[1];
    const float* Ro = (const float*)d_in[2];
    const float* W  = (const float*)d_in[3];
    const float* b  = (const float*)d_in[4];
    const float* te = (const float*)d_in[5];
    const float* tn = (const float*)d_in[6];
    float* out = (float*)d_out;

    int*   send = (int*)d_ws;
    int*   recv = send + N_EDGES;
    float* H    = (float*)(recv + N_EDGES);
    float* ebuf = H + N_NODES * 4;
    float* macc = ebuf + N_EDGES;

    int total4 = (N_NODES * N_EDGES) / 4;          // one float4 per thread
    k_setup<<<total4 / 256, 256, 0, stream>>>(X, Ri, Ro, W, b, send, recv, H);
    k_edge<<<N_EDGES / 4, 256, 0, stream>>>(H, send, recv, te, ebuf);
    for (int it = 0; it < 2; ++it) {
        hipMemsetAsync(macc, 0, N_NODES * 8 * sizeof(float), stream);
        k_scatter<<<N_EDGES / 256, 256, 0, stream>>>(ebuf, send, recv, H, macc);
        k_node<<<N_NODES / 4, 256, 0, stream>>>(macc, H, tn);
        float* dst = (it == 1) ? out : ebuf;
        k_edge<<<N_EDGES / 4, 256, 0, stream>>>(H, send, recv, te, dst);
    }
}

// Round 2
// 190.423 us; speedup vs baseline: 1.1441x; 1.1441x over previous
//
#include <hip/hip_runtime.h>
#include <math.h>

#define N_NODES 2048
#define N_EDGES 4096
#define PI_F 3.14159265358979323846f
#define TWO_PI_F 6.28318530717958647692f

__device__ __forceinline__ float shflx(float v, int m) {
    return __shfl_xor(v, m, 64);
}

// ---------------- gate helpers ----------------
// Amplitude index = lane*NA + j. j bits = in-register, lane bits above.
// RY pair semantics: new0 = c*s0 - s*s1 ; new1 = s*s0 + c*s1.

template<int NA, int B>
__device__ __forceinline__ void ry_j(float* a, float c, float s) {
#pragma unroll
    for (int j = 0; j < NA; ++j) {
        if ((j & (1 << B)) == 0) {
            int k = j | (1 << B);
            float x0 = a[j], x1 = a[k];
            a[j] = c * x0 - s * x1;
            a[k] = s * x0 + c * x1;
        }
    }
}

template<int NA, int LB>
__device__ __forceinline__ void ry_l(float* a, float c, float s, int lane) {
    float ss = ((lane >> LB) & 1) ? s : -s;
#pragma unroll
    for (int j = 0; j < NA; ++j) {
        float p = shflx(a[j], 1 << LB);
        a[j] = c * a[j] + ss * p;
    }
}

// CNOT helpers: flip tgt bit where ctrl bit == 1.
template<int NA, int BC, int BT>
__device__ __forceinline__ void cx_jj(float* a) {   // pure register rename
#pragma unroll
    for (int j = 0; j < NA; ++j) {
        if ((j & (1 << BC)) && !(j & (1 << BT))) {
            int k = j | (1 << BT);
            float t = a[j]; a[j] = a[k]; a[k] = t;
        }
    }
}

template<int NA, int LC, int BT>
__device__ __forceinline__ void cx_lj(float* a, int lane) {   // cndmask only, no shfl
    bool sel = ((lane >> LC) & 1) != 0;
#pragma unroll
    for (int j = 0; j < NA; ++j) {
        if ((j & (1 << BT)) == 0) {
            int k = j | (1 << BT);
            float t0 = a[j], t1 = a[k];
            a[j] = sel ? t1 : t0;
            a[k] = sel ? t0 : t1;
        }
    }
}

template<int NA, int LC, int LT>
__device__ __forceinline__ void cx_ll(float* a, int lane) {
    bool sel = ((lane >> LC) & 1) != 0;
#pragma unroll
    for (int j = 0; j < NA; ++j) {
        float p = shflx(a[j], 1 << LT);
        a[j] = sel ? p : a[j];
    }
}

// ---------------- setup: H0 + index extraction + macc zero + theta trig ----------------
__global__ __launch_bounds__(256) void k_setup(
        const float* __restrict__ X, const float* __restrict__ Ri,
        const float* __restrict__ Ro, const float* __restrict__ W,
        const float* __restrict__ b, const float* __restrict__ te,
        const float* __restrict__ tn,
        int* __restrict__ send, int* __restrict__ recv, float* __restrict__ H,
        float* __restrict__ maccA, float* __restrict__ maccB,
        float* __restrict__ trig) {
    int tid = blockIdx.x * blockDim.x + threadIdx.x;
    if (tid < N_NODES) {
        float x0 = X[tid*3+0], x1 = X[tid*3+1], x2 = X[tid*3+2];
        float z = x0*W[0] + x1*W[1] + x2*W[2] + b[0];
        float sg = 1.0f / (1.0f + expf(-z));
        H[tid*4+0] = sg * TWO_PI_F;
        H[tid*4+1] = x0; H[tid*4+2] = x1; H[tid*4+3] = x2;
    }
    if (tid < N_NODES * 8) { maccA[tid] = 0.f; maccB[tid] = 0.f; }
    if (tid >= 4096 && tid < 4096 + 15) {        // edge theta trig
        int i = tid - 4096; float s, c;
        sincosf(0.5f * te[i], &s, &c);
        trig[i] = c; trig[16 + i] = s;
    }
    if (tid >= 4224 && tid < 4224 + 23) {        // node theta trig
        int i = tid - 4224; float s, c;
        sincosf(0.5f * tn[i], &s, &c);
        trig[32 + i] = c; trig[56 + i] = s;
    }
    const float4 vi = ((const float4*)Ri)[tid];
    const float4 vo = ((const float4*)Ro)[tid];
    int base = tid * 4;
    int n = base >> 12;             // row (E = 4096)
    int e = base & (N_EDGES - 1);   // col
    if (vi.x != 0.f) recv[e+0] = n;
    if (vi.y != 0.f) recv[e+1] = n;
    if (vi.z != 0.f) recv[e+2] = n;
    if (vi.w != 0.f) recv[e+3] = n;
    if (vo.x != 0.f) send[e+0] = n;
    if (vo.y != 0.f) send[e+1] = n;
    if (vo.z != 0.f) send[e+2] = n;
    if (vo.w != 0.f) send[e+3] = n;
}

// ---------------- edge circuit: n=8, one wave/edge, 4 amps/lane ----------------
// bits [L5 L4 L3 L2 L1 L0 | J1 J0]; wires: w0=L5 w1=L4 w3=L3 w4=L2 w6=L1 w7=L0, w2=J1 w5=J0.
// All CNOTs except (0,1),(7,6) become shfl-free. Measure wire5 = J0.
template<bool SCATTER>
__global__ __launch_bounds__(256) void k_edge(
        const float* __restrict__ H, const int* __restrict__ send,
        const int* __restrict__ recv, const float* __restrict__ trig,
        float* __restrict__ out, float* __restrict__ macc) {
    int wave = (blockIdx.x * blockDim.x + threadIdx.x) >> 6;
    int lane = threadIdx.x & 63;
    int si = send[wave], ri = recv[wave];
    float B[8];
#pragma unroll
    for (int k = 0; k < 4; ++k) { B[k] = H[si*4+k]; B[4+k] = H[ri*4+k]; }

    // encoding trig
    float ec[8], es[8];
#pragma unroll
    for (int k = 0; k < 8; ++k) sincosf(0.5f * B[k], &es[k], &ec[k]);

    // product state: lane factor (wires 0,1,3,4,6,7 on L5..L0)
    float lp;
    {
        float f0 = ((lane>>5)&1) ? es[0] : ec[0];
        float f1 = ((lane>>4)&1) ? es[1] : ec[1];
        float f3 = ((lane>>3)&1) ? es[3] : ec[3];
        float f4 = ((lane>>2)&1) ? es[4] : ec[4];
        float f6 = ((lane>>1)&1) ? es[6] : ec[6];
        float f7 = ( lane     &1) ? es[7] : ec[7];
        lp = f0*f1*f3*f4*f6*f7;
    }
    float a[4];
    a[0] = lp;
    a[1] = a[0]*es[5]; a[0] *= ec[5];          // J0 = wire5
    a[2] = a[0]*es[2]; a[3] = a[1]*es[2];      // J1 = wire2
    a[0] *= ec[2];     a[1] *= ec[2];

    const float* tc = trig;        // cos(te/2)
    const float* ts = trig + 16;   // sin(te/2)

    ry_l<4,5>(a, tc[0], ts[0], lane);          // ry th0 w0
    ry_l<4,4>(a, tc[1], ts[1], lane);          // ry th1 w1
    cx_ll<4,5,4>(a, lane);                     // cx 0,1
    ry_j<4,1>(a, tc[2], ts[2]);                // ry th2 w2
    ry_l<4,3>(a, tc[3], ts[3], lane);          // ry th3 w3
    cx_lj<4,3,1>(a, lane);                     // cx 3,2
    ry_l<4,2>(a, tc[4], ts[4], lane);          // ry th4 w4
    ry_j<4,0>(a, tc[5], ts[5]);                // ry th5 w5
    cx_lj<4,2,0>(a, lane);                     // cx 4,5
    ry_l<4,1>(a, tc[6], ts[6], lane);          // ry th6 w6
    ry_l<4,0>(a, tc[7], ts[7], lane);          // ry th7 w7
    cx_ll<4,0,1>(a, lane);                     // cx 7,6
    ry_l<4,4>(a, tc[8], ts[8], lane);          // ry th8 w1
    ry_j<4,1>(a, tc[9], ts[9]);                // ry th9 w2
    cx_lj<4,4,1>(a, lane);                     // cx 1,2
    ry_j<4,0>(a, tc[10], ts[10]);              // ry th10 w5
    ry_l<4,1>(a, tc[11], ts[11], lane);        // ry th11 w6
    cx_lj<4,1,0>(a, lane);                     // cx 6,5
    ry_j<4,1>(a, tc[12], ts[12]);              // ry th12 w2
    ry_j<4,0>(a, tc[13], ts[13]);              // ry th13 w5
    cx_jj<4,1,0>(a);                           // cx 2,5
    ry_j<4,0>(a, tc[14], ts[14]);              // ry th14 w5

    // <Z> on wire5 = J0
    float p = (a[0]*a[0] + a[2]*a[2]) - (a[1]*a[1] + a[3]*a[3]);
#pragma unroll
    for (int m = 32; m; m >>= 1) p += shflx(p, m);
    float ev = (1.0f - p) * 0.5f;

    if (lane == 0) out[wave] = ev;
    if (SCATTER && lane < 8) {
        // mi[recv] += e*H[send] (B[0..3]) ; mo[send] += e*H[recv] (B[4..7])
        float bv = B[0];
        if (lane == 1) bv = B[1]; if (lane == 2) bv = B[2]; if (lane == 3) bv = B[3];
        if (lane == 4) bv = B[4]; if (lane == 5) bv = B[5]; if (lane == 6) bv = B[6];
        if (lane == 7) bv = B[7];
        int idx = (lane < 4) ? (ri*8 + lane) : (si*8 + 4 + (lane & 3));
        atomicAdd(&macc[idx], ev * bv);
    }
}

// ---------------- node circuit: n=12, one wave/node, 64 amps/lane ----------------
// bits [L5..L0 | J5..J0]; wires: L5=w0 L4=w3 L3=w4 L2=w7 L1=w8 L0=w11,
// J5=w1 J4=w2 J3=w5 J2=w6 J1=w9 J0=w10. All CNOTs shfl-free. Measure wire9 = J1.
__global__ __launch_bounds__(256) void k_node(
        const float* __restrict__ macc, float* __restrict__ H,
        const float* __restrict__ trig) {
    int wave = (blockIdx.x * blockDim.x + threadIdx.x) >> 6;
    int lane = threadIdx.x & 63;
    int n = wave;
    float M[12];
#pragma unroll
    for (int k = 0; k < 8; ++k) M[k] = macc[n*8+k];
#pragma unroll
    for (int k = 0; k < 4; ++k) M[8+k] = H[n*4+k];

    float mc[12], ms[12];
#pragma unroll
    for (int k = 0; k < 12; ++k) sincosf(0.5f * M[k], &ms[k], &mc[k]);

    // product state. lane wires: 0,3,4,7,8,11 on L5..L0
    float lp;
    {
        float f0  = ((lane>>5)&1) ? ms[0]  : mc[0];
        float f3  = ((lane>>4)&1) ? ms[3]  : mc[3];
        float f4  = ((lane>>3)&1) ? ms[4]  : mc[4];
        float f7  = ((lane>>2)&1) ? ms[7]  : mc[7];
        float f8  = ((lane>>1)&1) ? ms[8]  : mc[8];
        float f11 = ( lane    &1) ? ms[11] : mc[11];
        lp = f0*f3*f4*f7*f8*f11;
    }
    float a[64];
    a[0] = lp;
    // doubling over J0=w10, J1=w9, J2=w6, J3=w5, J4=w2, J5=w1
    {
        const int jw[6] = {10, 9, 6, 5, 2, 1};
#pragma unroll
        for (int bnum = 0; bnum < 6; ++bnum) {
            int sz = 1 << bnum;
            float cw = mc[jw[bnum]], sw = ms[jw[bnum]];
#pragma unroll
            for (int k = 0; k < 64; ++k) {
                if (k < sz) {
                    a[k + sz] = a[k] * sw;
                    a[k] *= cw;
                }
            }
        }
    }

    const float* tc = trig + 32;   // cos(tn/2)
    const float* ts = trig + 56;   // sin(tn/2)

    ry_l<64,5>(a, tc[0], ts[0], lane);         // th0 w0
    ry_j<64,5>(a, tc[1], ts[1]);               // th1 w1
    cx_lj<64,5,5>(a, lane);                    // cx 0,1
    ry_j<64,4>(a, tc[2], ts[2]);               // th2 w2
    ry_l<64,4>(a, tc[3], ts[3], lane);         // th3 w3
    cx_lj<64,4,4>(a, lane);                    // cx 3,2
    ry_l<64,3>(a, tc[4], ts[4], lane);         // th4 w4
    ry_j<64,3>(a, tc[5], ts[5]);               // th5 w5
    cx_lj<64,3,3>(a, lane);                    // cx 4,5
    ry_j<64,2>(a, tc[6], ts[6]);               // th6 w6
    ry_l<64,2>(a, tc[7], ts[7], lane);         // th7 w7
    cx_lj<64,2,2>(a, lane);                    // cx 7,6
    ry_l<64,1>(a, tc[8], ts[8], lane);         // th8 w8
    ry_j<64,1>(a, tc[9], ts[9]);               // th9 w9
    cx_lj<64,1,1>(a, lane);                    // cx 8,9
    ry_j<64,0>(a, tc[10], ts[10]);             // th10 w10
    ry_l<64,0>(a, tc[11], ts[11], lane);       // th11 w11
    cx_lj<64,0,0>(a, lane);                    // cx 11,10
    ry_j<64,5>(a, tc[12], ts[12]);             // th12 w1
    ry_j<64,4>(a, tc[13], ts[13]);             // th13 w2
    cx_jj<64,5,4>(a);                          // cx 1,2
    ry_j<64,3>(a, tc[14], ts[14]);             // th14 w5
    ry_j<64,2>(a, tc[15], ts[15]);             // th15 w6
    cx_jj<64,2,3>(a);                          // cx 6,5
    ry_j<64,1>(a, tc[16], ts[16]);             // th16 w9
    ry_j<64,0>(a, tc[17], ts[17]);             // th17 w10
    cx_jj<64,0,1>(a);                          // cx 10,9
    ry_j<64,4>(a, tc[18], ts[18]);             // th18 w2
    ry_j<64,3>(a, tc[19], ts[19]);             // th19 w5
    cx_jj<64,4,3>(a);                          // cx 2,5
    ry_j<64,3>(a, tc[20], ts[20]);             // th20 w5
    ry_j<64,1>(a, tc[21], ts[21]);             // th21 w9
    cx_jj<64,3,1>(a);                          // cx 5,9
    ry_l<64,3>(a, tc[22], ts[22], lane);       // th22 w4

    // <Z> on wire9 = J1
    float p = 0.f;
#pragma unroll
    for (int j = 0; j < 64; ++j) {
        float q = a[j]*a[j];
        p += (j & 2) ? -q : q;
    }
#pragma unroll
    for (int m = 32; m; m >>= 1) p += shflx(p, m);
    if (lane == 0) H[n*4+0] = PI_F * (1.0f - p);
}

extern "C" void kernel_launch(void* const* d_in, const int* in_sizes, int n_in,
                              void* d_out, int out_size, void* d_ws, size_t ws_size,
                              hipStream_t stream) {
    const float* X  = (const float*)d_in[0];
    const float* Ri = (const float*)d_in[1];
    const float* Ro = (const float*)d_in[2];
    const float* W  = (const float*)d_in[3];
    const float* b  = (const float*)d_in[4];
    const float* te = (const float*)d_in[5];
    const float* tn = (const float*)d_in[6];
    float* out = (float*)d_out;

    int*   send  = (int*)d_ws;
    int*   recv  = send + N_EDGES;
    float* H     = (float*)(recv + N_EDGES);
    float* ebuf  = H + N_NODES * 4;
    float* maccA = ebuf + N_EDGES;
    float* maccB = maccA + N_NODES * 8;
    float* trig  = maccB + N_NODES * 8;

    int total4 = (N_NODES * N_EDGES) / 4;
    k_setup<<<total4 / 256, 256, 0, stream>>>(X, Ri, Ro, W, b, te, tn,
                                              send, recv, H, maccA, maccB, trig);
    // it 0
    k_edge<true ><<<N_EDGES / 4, 256, 0, stream>>>(H, send, recv, trig, ebuf, maccA);
    k_node<<<N_NODES / 4, 256, 0, stream>>>(maccA, H, trig);
    // it 1
    k_edge<true ><<<N_EDGES / 4, 256, 0, stream>>>(H, send, recv, trig, ebuf, maccB);
    k_node<<<N_NODES / 4, 256, 0, stream>>>(maccB, H, trig);
    // final edge -> out
    k_edge<false><<<N_EDGES / 4, 256, 0, stream>>>(H, send, recv, trig, out, nullptr);
}